// Round 9
// baseline (6043.977 us; speedup 1.0000x reference)
//
#include <hip/hip_runtime.h>
#include <hip/hip_fp16.h>
#include <cstdint>
#include <cstddef>
#include <cstring>

#define T_SEQ 512
#define NB 32

__device__ __forceinline__ uint32_t agent_load_u32(const uint32_t* p) {
    return __hip_atomic_load(p, __ATOMIC_RELAXED, __HIP_MEMORY_SCOPE_AGENT);
}
__device__ __forceinline__ void agent_store_u32(uint32_t* p, uint32_t v) {
    __hip_atomic_store(p, v, __ATOMIC_RELAXED, __HIP_MEMORY_SCOPE_AGENT);
}
__device__ __forceinline__ __half2 u2h2(uint32_t u) {
    __half2 h; __builtin_memcpy(&h, &u, 4); return h;
}
// 8-half dot: acc += w[0..3] . hv  (both fp16 -> v_fma_mix)
__device__ __forceinline__ void dot8(float& a0, float& a1, float& a2, float& a3,
                                     const __half2* w, uint4 hv) {
    __half2 h;
    h = u2h2(hv.x);
    a0 = fmaf(__low2float(w[0]),  __low2float(h),  a0);
    a1 = fmaf(__high2float(w[0]), __high2float(h), a1);
    h = u2h2(hv.y);
    a2 = fmaf(__low2float(w[1]),  __low2float(h),  a2);
    a3 = fmaf(__high2float(w[1]), __high2float(h), a3);
    h = u2h2(hv.z);
    a0 = fmaf(__low2float(w[2]),  __low2float(h),  a0);
    a1 = fmaf(__high2float(w[2]), __high2float(h), a1);
    h = u2h2(hv.w);
    a2 = fmaf(__low2float(w[3]),  __low2float(h),  a2);
    a3 = fmaf(__high2float(w[3]), __high2float(h), a3);
}

// =====================================================================
// Phase A: layers 0+1 fused & software-pipelined (1 step apart).
// 256 blocks (= 8 row-slices x 32 batches) x 1024 threads, 1 block/CU.
// Thread (lane=tid&63 -> row s*64+lane, kq=tid>>6 in 0..15 -> k-chunk).
// VGPR weights (fp16): whh0 16 + wih0 4 + wih1 16 + whh1 16 = 52 half2
// (~85 regs total: under the ~92 compiler pressure target, r7 rule).
// Input projections fused: no GEMMs.
// Exchange: FULL-DEPTH tagged arrays xh0/xh1[b][t][512]:
//   word = (fp16(h)<<16) | (t+1).  Written once, never overwritten ->
// no reuse hazard, no back-pressure, deadlock-free by construction.
// Iteration it: compute h0(it) [it<512] and h1(it-1) [it>=1];
// polls: xh0 slot it-1 (tag it) and xh1 slot it-2 (tag it-1).
// Threads 0..511 poll xh0, 512..1023 poll xh1 (parallel).
// =====================================================================
__global__ __launch_bounds__(1024, 4) void rec01(
    const float* __restrict__ x,      // [NB,T,128]
    const float* __restrict__ Wih0, const float* __restrict__ Whh0,
    const float* __restrict__ bih0, const float* __restrict__ bhh0,
    const float* __restrict__ Wih1, const float* __restrict__ Whh1,
    const float* __restrict__ bih1, const float* __restrict__ bhh1,
    uint32_t* __restrict__ xh0,       // [NB][T][512]
    uint32_t* __restrict__ xh1)       // [NB][T][512]
{
    const int tid  = threadIdx.x;
    const int b    = blockIdx.x & 31;
    const int s    = blockIdx.x >> 5;     // 0..7
    const int lane = tid & 63;
    const int kq   = tid >> 6;            // 0..15
    const int row  = (s << 6) + lane;

    __shared__ unsigned short h0buf[512];   // fp16 bits of h0(it-1)
    __shared__ unsigned short r0buf[512];   // relu(h0(it-1))
    __shared__ unsigned short h1buf[512];   // h1(it-2)
    __shared__ float xbuf[2][128];
    __shared__ float part0[16][64];
    __shared__ float part1[16][64];

    // ---- weights -> fp16 VGPRs ----
    __half2 whh0[16], wih0[4], wih1[16], whh1[16];
    {
        const float* p = Whh0 + (size_t)row * 512 + (kq << 5);
#pragma unroll
        for (int i = 0; i < 16; i++) whh0[i] = __floats2half2_rn(p[2*i], p[2*i+1]);
        const float* q = Wih0 + (size_t)row * 128 + (kq << 3);
#pragma unroll
        for (int i = 0; i < 4; i++)  wih0[i] = __floats2half2_rn(q[2*i], q[2*i+1]);
        p = Wih1 + (size_t)row * 512 + (kq << 5);
#pragma unroll
        for (int i = 0; i < 16; i++) wih1[i] = __floats2half2_rn(p[2*i], p[2*i+1]);
        p = Whh1 + (size_t)row * 512 + (kq << 5);
#pragma unroll
        for (int i = 0; i < 16; i++) whh1[i] = __floats2half2_rn(p[2*i], p[2*i+1]);
    }
    float bias0 = 0.f, bias1 = 0.f;
    if (tid < 64)        bias0 = bih0[row] + bhh0[row];
    else if (tid < 128)  { const int r2 = (s << 6) + (tid - 64); bias1 = bih1[r2] + bhh1[r2]; }

    // zero h-bufs (h(-1) = 0)
    if (tid < 256) {
        ((uint32_t*)h0buf)[tid] = 0;
        ((uint32_t*)r0buf)[tid] = 0;
        ((uint32_t*)h1buf)[tid] = 0;
    }
    const float* x_b = x + (size_t)b * (T_SEQ * 128);
    if (tid < 128) xbuf[0][tid] = x_b[tid];
    __syncthreads();

    uint32_t* xh0_b = xh0 + ((size_t)b << 18);
    uint32_t* xh1_b = xh1 + ((size_t)b << 18);
    const int own_lo = s << 6, own_hi = (s << 6) + 64;

    for (int it = 0; it <= T_SEQ; ++it) {
        // stage x(it+1) (off critical path)
        if (tid < 128 && it + 1 < T_SEQ) xbuf[(it + 1) & 1][tid] = x_b[(it + 1) * 128 + tid];

        // ---- polls + decode ----
        if (tid < 512) {
            if (it >= 1 && !(tid >= own_lo && tid < own_hi)) {
                uint32_t* wp = xh0_b + (size_t)(it - 1) * 512 + tid;
                const uint32_t wtag = (uint32_t)it;
                uint32_t v;
                do { v = agent_load_u32(wp); } while ((v & 0xffffu) != wtag);
                const unsigned short us = (unsigned short)(v >> 16);
                h0buf[tid] = us;
                r0buf[tid] = (us & 0x8000u) ? (unsigned short)0 : us;
            }
        } else {
            const int w = tid - 512;
            if (it >= 2 && !(w >= own_lo && w < own_hi)) {
                uint32_t* wp = xh1_b + (size_t)(it - 2) * 512 + w;
                const uint32_t wtag = (uint32_t)(it - 1);
                uint32_t v;
                do { v = agent_load_u32(wp); } while ((v & 0xffffu) != wtag);
                h1buf[w] = (unsigned short)(v >> 16);
            }
        }
        __syncthreads();   // B1

        // ---- compute ----
        float a0 = 0.f, a1 = 0.f, a2 = 0.f, a3 = 0.f;   // L0: h0(it)
        float c0 = 0.f, c1 = 0.f, c2 = 0.f, c3 = 0.f;   // L1: h1(it-1)
        {
            const uint4* h0q = (const uint4*)((const uint32_t*)h0buf + (kq << 4));
            const uint4* r0q = (const uint4*)((const uint32_t*)r0buf + (kq << 4));
            const uint4* h1q = (const uint4*)((const uint32_t*)h1buf + (kq << 4));
#pragma unroll
            for (int i = 0; i < 4; i++) dot8(a0, a1, a2, a3, &whh0[4 * i], h0q[i]);
            const int p = it & 1;
#pragma unroll
            for (int i = 0; i < 4; i++) {
                a0 = fmaf(__low2float(wih0[i]),  xbuf[p][(kq << 3) + 2 * i],     a0);
                a1 = fmaf(__high2float(wih0[i]), xbuf[p][(kq << 3) + 2 * i + 1], a1);
            }
#pragma unroll
            for (int i = 0; i < 4; i++) dot8(c0, c1, c2, c3, &wih1[4 * i], r0q[i]);
#pragma unroll
            for (int i = 0; i < 4; i++) dot8(c0, c1, c2, c3, &whh1[4 * i], h1q[i]);
        }
        part0[kq][lane] = (a0 + a1) + (a2 + a3);
        part1[kq][lane] = (c0 + c1) + (c2 + c3);
        __syncthreads();   // B2

        // ---- epilogues (two waves in parallel) ----
        if (tid < 64) {
            if (it < T_SEQ) {
                float v = bias0;
#pragma unroll
                for (int q = 0; q < 16; q++) v += part0[q][tid];
                const float h = tanhf(v);
                const __half hf = __float2half_rn(h);
                unsigned short us; __builtin_memcpy(&us, &hf, 2);
                agent_store_u32(xh0_b + (size_t)it * 512 + row,
                                ((uint32_t)us << 16) | (uint32_t)(it + 1));
                h0buf[row] = us;
                r0buf[row] = (us & 0x8000u) ? (unsigned short)0 : us;
            }
        } else if (tid < 128) {
            if (it >= 1) {
                const int l2 = tid - 64, r2 = (s << 6) + l2;
                float v = bias1;
#pragma unroll
                for (int q = 0; q < 16; q++) v += part1[q][l2];
                const float h = tanhf(v);
                const __half hf = __float2half_rn(h);
                unsigned short us; __builtin_memcpy(&us, &hf, 2);
                agent_store_u32(xh1_b + (size_t)(it - 1) * 512 + r2,
                                ((uint32_t)us << 16) | (uint32_t)it);
                h1buf[r2] = us;
            }
        }
        // no trailing barrier: next B1 orders everything
    }
}

// =====================================================================
// Phase B: layer 2 (H=128) fused with its input projection.
// 32 independent blocks (1/batch) x 1024 threads; xh1 fully materialized
// by phase A (stream order) -> polls hit immediately. Weights in VGPRs:
// wih2 32 half2 + whh2 8 half2 (~65 regs).
// Thread (j=tid&127, kh=tid>>7 in 0..7): ih k-range 64, hh k-range 16.
// =====================================================================
__global__ __launch_bounds__(1024, 4) void rec2(
    const float* __restrict__ Wih2, const float* __restrict__ Whh2,
    const float* __restrict__ bih2, const float* __restrict__ bhh2,
    const uint32_t* __restrict__ xh1,   // [NB][T][512]
    float* __restrict__ out,            // [NB,T,128]
    float* __restrict__ hn)             // [NB,128]
{
    const int tid = threadIdx.x;
    const int b   = blockIdx.x;
    const int j   = tid & 127;
    const int kh  = tid >> 7;          // 0..7

    __shared__ unsigned short r1buf[512];
    __shared__ unsigned short h2buf[128];
    __shared__ float part[8][128];

    __half2 wih2[32], whh2[8];
    {
        const float* p = Wih2 + (size_t)j * 512 + (kh << 6);
#pragma unroll
        for (int i = 0; i < 32; i++) wih2[i] = __floats2half2_rn(p[2*i], p[2*i+1]);
        const float* q = Whh2 + (size_t)j * 128 + (kh << 4);
#pragma unroll
        for (int i = 0; i < 8; i++)  whh2[i] = __floats2half2_rn(q[2*i], q[2*i+1]);
    }
    float bias2 = 0.f;
    if (tid < 128) bias2 = bih2[j] + bhh2[j];
    if (tid < 64) ((uint32_t*)h2buf)[tid] = 0;
    __syncthreads();

    const uint32_t* xh1_b = xh1 + ((size_t)b << 18);
    float* out_b = out + (size_t)b * (T_SEQ * 128);

    for (int t = 0; t < T_SEQ; ++t) {
        if (tid < 512) {
            const uint32_t* wp = xh1_b + (size_t)t * 512 + tid;
            const uint32_t wtag = (uint32_t)(t + 1);
            uint32_t v;
            do { v = agent_load_u32((const uint32_t*)wp); } while ((v & 0xffffu) != wtag);
            const unsigned short us = (unsigned short)(v >> 16);
            r1buf[tid] = (us & 0x8000u) ? (unsigned short)0 : us;
        }
        __syncthreads();   // B1

        float a0 = 0.f, a1 = 0.f, a2 = 0.f, a3 = 0.f;
        {
            const uint4* rq = (const uint4*)((const uint32_t*)r1buf + (kh << 5));
#pragma unroll
            for (int i = 0; i < 8; i++) dot8(a0, a1, a2, a3, &wih2[4 * i], rq[i]);
            const uint4* hq = (const uint4*)((const uint32_t*)h2buf + (kh << 3));
#pragma unroll
            for (int i = 0; i < 2; i++) dot8(a0, a1, a2, a3, &whh2[4 * i], hq[i]);
        }
        part[kh][j] = (a0 + a1) + (a2 + a3);
        __syncthreads();   // B2

        if (tid < 128) {
            float v = bias2;
#pragma unroll
            for (int q = 0; q < 8; q++) v += part[q][tid];
            const float h = tanhf(v);
            out_b[t * 128 + tid] = h;
            const __half hf = __float2half_rn(h);
            unsigned short us; __builtin_memcpy(&us, &hf, 2);
            h2buf[tid] = us;
            if (t == T_SEQ - 1) hn[b * 128 + tid] = h;
        }
        // next B1 orders h2buf/r1buf reuse
    }
}

// =====================================================================
// Launch: 2 kernels, no GEMMs, no memsets.
// ws: xh0 33.55 MB + xh1 33.55 MB = 67.1 MB.
// =====================================================================
extern "C" void kernel_launch(void* const* d_in, const int* in_sizes, int n_in,
                              void* d_out, int out_size, void* d_ws, size_t ws_size,
                              hipStream_t stream)
{
    const float* x    = (const float*)d_in[0];
    const float* Wih0 = (const float*)d_in[1];
    const float* Whh0 = (const float*)d_in[2];
    const float* bih0 = (const float*)d_in[3];
    const float* bhh0 = (const float*)d_in[4];
    const float* Wih1 = (const float*)d_in[5];
    const float* Whh1 = (const float*)d_in[6];
    const float* bih1 = (const float*)d_in[7];
    const float* bhh1 = (const float*)d_in[8];
    const float* Wih2 = (const float*)d_in[9];
    const float* Whh2 = (const float*)d_in[10];
    const float* bih2 = (const float*)d_in[11];
    const float* bhh2 = (const float*)d_in[12];

    uint32_t* xh0 = (uint32_t*)d_ws;              // [32][512][512]
    uint32_t* xh1 = xh0 + ((size_t)NB << 18);     // [32][512][512]

    float* out = (float*)d_out;                   // [32,512,128]
    float* hn  = out + NB * T_SEQ * 128;          // [1,32,128]

    rec01<<<NB * 8, 1024, 0, stream>>>(x, Wih0, Whh0, bih0, bhh0,
                                       Wih1, Whh1, bih1, bhh1, xh0, xh1);
    rec2<<<NB, 1024, 0, stream>>>(Wih2, Whh2, bih2, bhh2, xh1, out, hn);
}

// Round 10
// 3113.860 us; speedup vs baseline: 1.9410x; 1.9410x over previous
//
#include <hip/hip_runtime.h>
#include <hip/hip_fp16.h>
#include <cstdint>
#include <cstddef>
#include <cstring>

#define T_SEQ 512
#define NB 32

__device__ __forceinline__ uint32_t agent_load_u32(const uint32_t* p) {
    return __hip_atomic_load(p, __ATOMIC_RELAXED, __HIP_MEMORY_SCOPE_AGENT);
}
__device__ __forceinline__ void agent_store_u32(uint32_t* p, uint32_t v) {
    __hip_atomic_store(p, v, __ATOMIC_RELAXED, __HIP_MEMORY_SCOPE_AGENT);
}
__device__ __forceinline__ float hbits2f(unsigned short us) {
    __half h; __builtin_memcpy(&h, &us, 2); return __half2float(h);
}

// =====================================================================
// GEMM (fp32 A): C[M,N] = A @ W^T + (bi+bh).  (proven r2) — layer-0 xp.
// =====================================================================
#define BM 64
#define BN 128
#define BK 32
#define AS_STRIDE 68
#define BS_STRIDE 132

__global__ __launch_bounds__(256, 4) void gemm_xp(
    const float* __restrict__ A, const float* __restrict__ W,
    const float* __restrict__ bi, const float* __restrict__ bh,
    float* __restrict__ C, int M, int N, int K)
{
    __shared__ float As[BK][AS_STRIDE];
    __shared__ float Bs[BK][BS_STRIDE];
    const int tid = threadIdx.x;
    const int tx = tid & 15, ty = tid >> 4;
    const int m0 = blockIdx.x * BM, n0 = blockIdx.y * BN;
    const int lr = tid >> 3, lc = (tid & 7) << 2;

    float acc[4][8];
#pragma unroll
    for (int i = 0; i < 4; i++)
#pragma unroll
        for (int j = 0; j < 8; j++) acc[i][j] = 0.f;

    for (int k0 = 0; k0 < K; k0 += BK) {
#pragma unroll
        for (int p = 0; p < 2; p++) {
            const int m = p * 32 + lr;
            const float4 a4 = *(const float4*)(A + (size_t)(m0 + m) * K + k0 + lc);
            As[lc + 0][m] = a4.x; As[lc + 1][m] = a4.y;
            As[lc + 2][m] = a4.z; As[lc + 3][m] = a4.w;
        }
#pragma unroll
        for (int p = 0; p < 4; p++) {
            const int n = p * 32 + lr;
            const float4 b4 = *(const float4*)(W + (size_t)(n0 + n) * K + k0 + lc);
            Bs[lc + 0][n] = b4.x; Bs[lc + 1][n] = b4.y;
            Bs[lc + 2][n] = b4.z; Bs[lc + 3][n] = b4.w;
        }
        __syncthreads();
#pragma unroll
        for (int kk = 0; kk < BK; kk++) {
            const float4 a4  = *(const float4*)&As[kk][tx << 2];
            const float4 b4a = *(const float4*)&Bs[kk][ty << 3];
            const float4 b4b = *(const float4*)&Bs[kk][(ty << 3) + 4];
            const float a[4] = { a4.x, a4.y, a4.z, a4.w };
            const float b[8] = { b4a.x, b4a.y, b4a.z, b4a.w, b4b.x, b4b.y, b4b.z, b4b.w };
#pragma unroll
            for (int i = 0; i < 4; i++)
#pragma unroll
                for (int j = 0; j < 8; j++) acc[i][j] = fmaf(a[i], b[j], acc[i][j]);
        }
        __syncthreads();
    }
    const int nbase = n0 + (ty << 3);
    const float4 bia = *(const float4*)(bi + nbase);
    const float4 bib = *(const float4*)(bi + nbase + 4);
    const float4 bha = *(const float4*)(bh + nbase);
    const float4 bhb = *(const float4*)(bh + nbase + 4);
    const float bt[8] = { bia.x + bha.x, bia.y + bha.y, bia.z + bha.z, bia.w + bha.w,
                          bib.x + bhb.x, bib.y + bhb.y, bib.z + bhb.z, bib.w + bhb.w };
#pragma unroll
    for (int i = 0; i < 4; i++) {
        const int row = m0 + (tx << 2) + i;
        float4 o1, o2;
        o1.x = acc[i][0] + bt[0]; o1.y = acc[i][1] + bt[1];
        o1.z = acc[i][2] + bt[2]; o1.w = acc[i][3] + bt[3];
        o2.x = acc[i][4] + bt[4]; o2.y = acc[i][5] + bt[5];
        o2.z = acc[i][6] + bt[6]; o2.w = acc[i][7] + bt[7];
        *(float4*)(C + (size_t)row * N + nbase)     = o1;
        *(float4*)(C + (size_t)row * N + nbase + 4) = o2;
    }
}

// =====================================================================
// Layers 0+1, pipelined across SEPARATE role-blocks (one kernel).
// 512 blocks x 512 threads, __launch_bounds__(512,4): 2 blocks/CU,
// capacity = 512 => all blocks resident (no dispatch deadlock).
//
// role 0 (bid<256): EXACT r7 rec_h512 loop on Whh0/xp0:
//   parity-tagged hpk0 exchange (proven), register xp prefetch,
//   plus: publish relu(h0(t)) to xr0[b][t][256] as packed fp16 PAIRS.
//   Validity by SIGN BITS: relu fp16 has bit15==0; ws poison 0xAAAA has
//   bit15==1 -> word valid iff (v & 0x80008000)==0. Written once, never
//   overwritten: no tags, no back-pressure, overwrite-impossible.
// role 1 (bid>=256): step u polls xr0(u) (role-0 leads ~1 step -> lines
//   LLC-hot, ~1 round), computes Wih1·r0(u) + Whh1·h1(u-1) with 64 half2
//   VGPR weights (~80 regs < the ~92 remat threshold, r7 rule),
//   exchanges h1 via parity-tagged hpk1 (r7 protocol), writes
//   relu(h1(u)) as fp16 to relu1 for gemm2h.
// Deadlock-free: role-0 waits only on role-0 peers (r7-proven);
// role-1 waits on xr0 (independent producer) + role-1 peers. Acyclic.
// =====================================================================
__global__ __launch_bounds__(512, 4) void rec01(
    const float* __restrict__ Whh0,     // [512,512]
    const float* __restrict__ xp0,      // [NB,T,512] f32 (biases included)
    const float* __restrict__ Wih1,     // [512,512]
    const float* __restrict__ Whh1,     // [512,512]
    const float* __restrict__ bih1, const float* __restrict__ bhh1,
    uint32_t* __restrict__ xr0,         // [NB][T][256] packed relu-h0
    unsigned short* __restrict__ relu1, // [NB][T][512] fp16 bits
    uint32_t* __restrict__ hpk0,        // [NB][2][512]
    uint32_t* __restrict__ hpk1)        // [NB][2][512]
{
    const int tid = threadIdx.x;
    const int role = blockIdx.x >> 8;
    const int sub  = blockIdx.x & 255;
    const int b = sub & 31;
    const int s = sub >> 5;           // 0..7
    const int jl = tid & 63;
    const int kq = tid >> 6;          // 0..7, wave-uniform
    const bool own = (kq == s);

    if (role == 0) {
        // ---------------- layer 0 (r7 structure) ----------------
        __shared__ float hbuf[2][512];
        __shared__ float part[8][64];

        __half2 w[32];
        {
            const float4* wp4 = (const float4*)(Whh0 + (size_t)((s << 6) + jl) * 512 + (kq << 6));
#pragma unroll
            for (int i = 0; i < 16; i++) {
                const float4 v = wp4[i];
                w[2 * i]     = __floats2half2_rn(v.x, v.y);
                w[2 * i + 1] = __floats2half2_rn(v.z, v.w);
            }
        }
        uint32_t* hp_b = hpk0 + (b << 10);
        uint32_t* xr_b = xr0 + ((size_t)b * T_SEQ * 256);
        const float* xp_b = xp0 + (size_t)b * (T_SEQ * 512);
        const int myrow = (s << 6) + tid;            // valid for tid<64

        float xpv = (tid < 64) ? xp_b[myrow] : 0.f;

        for (int t = 0; t < T_SEQ; t++) {
            const int p = t & 1;
            float xpn = (tid < 64 && t + 1 < T_SEQ) ? xp_b[(t + 1) * 512 + myrow] : 0.f;

            float a0 = 0.f, a1 = 0.f, a2 = 0.f, a3 = 0.f;
            if (t > 0) {
                if (!own) {
                    const uint32_t wtag = (uint32_t)t;
                    uint32_t* sp = hp_b + (p << 9) + tid;
                    uint32_t v;
                    do { v = agent_load_u32(sp); } while ((v & 0xffffu) != wtag);
                    hbuf[p][tid] = hbits2f((unsigned short)(v >> 16));
                }
                __syncthreads();   // B1
                const float4* hq = (const float4*)(&hbuf[p][kq << 6]);
#pragma unroll
                for (int i = 0; i < 16; i++) {
                    const float4 h4 = hq[i];
                    a0 = fmaf(__low2float(w[2 * i]),      h4.x, a0);
                    a1 = fmaf(__high2float(w[2 * i]),     h4.y, a1);
                    a2 = fmaf(__low2float(w[2 * i + 1]),  h4.z, a2);
                    a3 = fmaf(__high2float(w[2 * i + 1]), h4.w, a3);
                }
            }
            part[kq][jl] = (a0 + a1) + (a2 + a3);
            __syncthreads();       // B2
            if (tid < 64) {
                const int p2 = (t + 1) & 1;
                float v = xpv;
#pragma unroll
                for (int q = 0; q < 8; q++) v += part[q][tid];
                const float hv = tanhf(v);
                const __half hf = __float2half_rn(hv);
                unsigned short us; __builtin_memcpy(&us, &hf, 2);
                agent_store_u32(hp_b + (p2 << 9) + myrow,
                                ((uint32_t)us << 16) | (uint32_t)(t + 1));
                // publish relu(h0) pair (sign-validating, full depth)
                const unsigned short usr = (us & 0x8000u) ? (unsigned short)0 : us;
                const uint32_t up = ((uint32_t)(unsigned short)__shfl_down((int)usr, 1) << 16)
                                    | (uint32_t)usr;
                if (!(tid & 1))
                    agent_store_u32(xr_b + (size_t)t * 256 + (myrow >> 1), up);
                hbuf[p2][myrow] = hbits2f(us);
            }
            xpv = xpn;
        }
    } else {
        // ---------------- layer 1 (pipelined consumer) ----------------
        __shared__ float r0buf[512];
        __shared__ float h1buf[2][512];
        __shared__ float part1[8][64];

        __half2 wi[32], wh[32];
        {
            const float4* p4 = (const float4*)(Wih1 + (size_t)((s << 6) + jl) * 512 + (kq << 6));
#pragma unroll
            for (int i = 0; i < 16; i++) {
                const float4 v = p4[i];
                wi[2 * i]     = __floats2half2_rn(v.x, v.y);
                wi[2 * i + 1] = __floats2half2_rn(v.z, v.w);
            }
            p4 = (const float4*)(Whh1 + (size_t)((s << 6) + jl) * 512 + (kq << 6));
#pragma unroll
            for (int i = 0; i < 16; i++) {
                const float4 v = p4[i];
                wh[2 * i]     = __floats2half2_rn(v.x, v.y);
                wh[2 * i + 1] = __floats2half2_rn(v.z, v.w);
            }
        }
        float bias1 = 0.f;
        if (tid < 64) {
            const int r = (s << 6) + tid;
            bias1 = bih1[r] + bhh1[r];
        }
        uint32_t* hp_b = hpk1 + (b << 10);
        const uint32_t* xr_b = xr0 + ((size_t)b * T_SEQ * 256);
        unsigned short* r1_b = relu1 + (size_t)b * (T_SEQ * 512);
        const int myrow = (s << 6) + tid;            // valid for tid<64

        h1buf[0][tid] = 0.f;     // h1(-1) = 0 (parity 0)
        __syncthreads();

        for (int u = 0; u < T_SEQ; u++) {
            const int p = u & 1;
            // poll xr0(u): 256 lanes, sign-validated pairs (LLC-hot: lag ~1)
            if (tid < 256) {
                const uint32_t* wp = xr_b + (size_t)u * 256 + tid;
                uint32_t v;
                do { v = agent_load_u32(wp); } while (v & 0x80008000u);
                r0buf[2 * tid]     = hbits2f((unsigned short)(v & 0xffffu));
                r0buf[2 * tid + 1] = hbits2f((unsigned short)(v >> 16));
            }
            // poll h1(u-1) from peers (parity-tagged, r7 protocol)
            if (u > 0 && !own) {
                const uint32_t wtag = (uint32_t)u;
                uint32_t* sp = hp_b + (p << 9) + tid;
                uint32_t v;
                do { v = agent_load_u32(sp); } while ((v & 0xffffu) != wtag);
                h1buf[p][tid] = hbits2f((unsigned short)(v >> 16));
            }
            __syncthreads();   // B1
            float a0 = 0.f, a1 = 0.f, a2 = 0.f, a3 = 0.f;
            {
                const float4* rq = (const float4*)(&r0buf[kq << 6]);
                const float4* hq = (const float4*)(&h1buf[p][kq << 6]);
#pragma unroll
                for (int i = 0; i < 16; i++) {
                    const float4 h4 = rq[i];
                    a0 = fmaf(__low2float(wi[2 * i]),      h4.x, a0);
                    a1 = fmaf(__high2float(wi[2 * i]),     h4.y, a1);
                    a2 = fmaf(__low2float(wi[2 * i + 1]),  h4.z, a2);
                    a3 = fmaf(__high2float(wi[2 * i + 1]), h4.w, a3);
                }
#pragma unroll
                for (int i = 0; i < 16; i++) {
                    const float4 h4 = hq[i];
                    a0 = fmaf(__low2float(wh[2 * i]),      h4.x, a0);
                    a1 = fmaf(__high2float(wh[2 * i]),     h4.y, a1);
                    a2 = fmaf(__low2float(wh[2 * i + 1]),  h4.z, a2);
                    a3 = fmaf(__high2float(wh[2 * i + 1]), h4.w, a3);
                }
            }
            part1[kq][jl] = (a0 + a1) + (a2 + a3);
            __syncthreads();   // B2
            if (tid < 64) {
                const int p2 = (u + 1) & 1;
                float v = bias1;
#pragma unroll
                for (int q = 0; q < 8; q++) v += part1[q][tid];
                const float hv = tanhf(v);
                const __half hf = __float2half_rn(hv);
                unsigned short us; __builtin_memcpy(&us, &hf, 2);
                agent_store_u32(hp_b + (p2 << 9) + myrow,
                                ((uint32_t)us << 16) | (uint32_t)(u + 1));
                h1buf[p2][myrow] = hbits2f(us);
                r1_b[(size_t)u * 512 + myrow] = (us & 0x8000u) ? (unsigned short)0 : us;
            }
        }
    }
}

// =====================================================================
// gemm2h: xp2 = relu1(fp16) @ Wih2^T + (bi+bh), output fp16.
// M=16384, N=128 (single tile column), K=512.
// =====================================================================
__global__ __launch_bounds__(256, 4) void gemm2h(
    const unsigned short* __restrict__ A,   // [M,512] fp16 bits
    const float* __restrict__ W,            // [128,512]
    const float* __restrict__ bi, const float* __restrict__ bh,
    unsigned short* __restrict__ C,         // [M,128] fp16 bits
    int M, int K)
{
    __shared__ float As[BK][AS_STRIDE];
    __shared__ float Bs[BK][BS_STRIDE];
    const int tid = threadIdx.x;
    const int tx = tid & 15, ty = tid >> 4;
    const int m0 = blockIdx.x * BM;
    const int lr = tid >> 3, lc = (tid & 7) << 2;

    float acc[4][8];
#pragma unroll
    for (int i = 0; i < 4; i++)
#pragma unroll
        for (int j = 0; j < 8; j++) acc[i][j] = 0.f;

    for (int k0 = 0; k0 < K; k0 += BK) {
#pragma unroll
        for (int p = 0; p < 2; p++) {
            const int m = p * 32 + lr;
            const uint2 u = *(const uint2*)(A + (size_t)(m0 + m) * K + k0 + lc);
            As[lc + 0][m] = hbits2f((unsigned short)(u.x & 0xffffu));
            As[lc + 1][m] = hbits2f((unsigned short)(u.x >> 16));
            As[lc + 2][m] = hbits2f((unsigned short)(u.y & 0xffffu));
            As[lc + 3][m] = hbits2f((unsigned short)(u.y >> 16));
        }
#pragma unroll
        for (int p = 0; p < 4; p++) {
            const int n = p * 32 + lr;
            const float4 b4 = *(const float4*)(W + (size_t)n * K + k0 + lc);
            Bs[lc + 0][n] = b4.x; Bs[lc + 1][n] = b4.y;
            Bs[lc + 2][n] = b4.z; Bs[lc + 3][n] = b4.w;
        }
        __syncthreads();
#pragma unroll
        for (int kk = 0; kk < BK; kk++) {
            const float4 a4  = *(const float4*)&As[kk][tx << 2];
            const float4 b4a = *(const float4*)&Bs[kk][ty << 3];
            const float4 b4b = *(const float4*)&Bs[kk][(ty << 3) + 4];
            const float a[4] = { a4.x, a4.y, a4.z, a4.w };
            const float b[8] = { b4a.x, b4a.y, b4a.z, b4a.w, b4b.x, b4b.y, b4b.z, b4b.w };
#pragma unroll
            for (int i = 0; i < 4; i++)
#pragma unroll
                for (int j = 0; j < 8; j++) acc[i][j] = fmaf(a[i], b[j], acc[i][j]);
        }
        __syncthreads();
    }
    const int nbase = ty << 3;
    const float4 bia = *(const float4*)(bi + nbase);
    const float4 bib = *(const float4*)(bi + nbase + 4);
    const float4 bha = *(const float4*)(bh + nbase);
    const float4 bhb = *(const float4*)(bh + nbase + 4);
    const float bt[8] = { bia.x + bha.x, bia.y + bha.y, bia.z + bha.z, bia.w + bha.w,
                          bib.x + bhb.x, bib.y + bhb.y, bib.z + bhb.z, bib.w + bhb.w };
#pragma unroll
    for (int i = 0; i < 4; i++) {
        const int row = m0 + (tx << 2) + i;
        uint32_t pk[4];
#pragma unroll
        for (int j = 0; j < 4; j++) {
            const __half hlo = __float2half_rn(acc[i][2 * j]     + bt[2 * j]);
            const __half hhi = __float2half_rn(acc[i][2 * j + 1] + bt[2 * j + 1]);
            unsigned short lo, hi;
            __builtin_memcpy(&lo, &hlo, 2); __builtin_memcpy(&hi, &hhi, 2);
            pk[j] = ((uint32_t)hi << 16) | lo;
        }
        *(uint4*)(C + (size_t)row * 128 + nbase) = make_uint4(pk[0], pk[1], pk[2], pk[3]);
    }
}

// =====================================================================
// Layer 2 recurrence (H=128), xp in fp16. One WG per batch; LDS-only.
// =====================================================================
__global__ __launch_bounds__(256, 4) void rec128h(
    const float* __restrict__ Whh,          // [128,128]
    const unsigned short* __restrict__ xp,  // [NB,T,128] fp16 bits
    float* __restrict__ out,                // [NB,T,128]
    float* __restrict__ hn)                 // [NB,128]
{
    const int tid = threadIdx.x;
    const int b  = blockIdx.x;
    const int j  = tid & 127;
    const int kh = tid >> 7;

    __shared__ float hbuf[2][128];
    __shared__ float part[2][128];

    float w[64];
    {
        const float4* wp = (const float4*)(Whh + (size_t)j * 128 + (kh << 6));
#pragma unroll
        for (int i = 0; i < 16; i++) {
            const float4 v = wp[i];
            w[4 * i + 0] = v.x; w[4 * i + 1] = v.y;
            w[4 * i + 2] = v.z; w[4 * i + 3] = v.w;
        }
    }

    const unsigned short* xp_b = xp + (size_t)b * (T_SEQ * 128);
    float* out_b = out + (size_t)b * (T_SEQ * 128);

    float xpv = (tid < 128) ? hbits2f(xp_b[tid]) : 0.f;

    for (int t = 0; t < T_SEQ; t++) {
        float xpn = (tid < 128 && t + 1 < T_SEQ) ? hbits2f(xp_b[(t + 1) * 128 + tid]) : 0.f;

        float a0 = 0.f, a1 = 0.f, a2 = 0.f, a3 = 0.f;
        if (t > 0) {
            const float4* hq = (const float4*)(&hbuf[t & 1][kh << 6]);
#pragma unroll
            for (int i = 0; i < 16; i++) {
                const float4 h4 = hq[i];
                a0 = fmaf(w[4 * i + 0], h4.x, a0);
                a1 = fmaf(w[4 * i + 1], h4.y, a1);
                a2 = fmaf(w[4 * i + 2], h4.z, a2);
                a3 = fmaf(w[4 * i + 3], h4.w, a3);
            }
        }
        part[kh][j] = (a0 + a1) + (a2 + a3);
        __syncthreads();
        if (tid < 128) {
            const float v = part[0][tid] + part[1][tid] + xpv;
            const float h = tanhf(v);
            hbuf[(t + 1) & 1][tid] = h;
            out_b[t * 128 + tid] = h;
            if (t == T_SEQ - 1) hn[b * 128 + tid] = h;
        }
        __syncthreads();
        xpv = xpn;
    }
}

// =====================================================================
// Launch.  ws layout (bytes):
//   buf0 (xp0 f32)   @ 0          33,554,432
//   xr0  (u32 pairs) @ 33,554,432 16,777,216
//   relu1 (u16)      @ 50,331,648 16,777,216
//   xp2h (u16)       @ 67,108,864  4,194,304
//   hpk0 (u32)       @ 71,303,168    131,072
//   hpk1 (u32)       @ 71,434,240    131,072   -> total 71,565,312
// =====================================================================
extern "C" void kernel_launch(void* const* d_in, const int* in_sizes, int n_in,
                              void* d_out, int out_size, void* d_ws, size_t ws_size,
                              hipStream_t stream)
{
    const float* x    = (const float*)d_in[0];
    const float* Wih0 = (const float*)d_in[1];
    const float* Whh0 = (const float*)d_in[2];
    const float* bih0 = (const float*)d_in[3];
    const float* bhh0 = (const float*)d_in[4];
    const float* Wih1 = (const float*)d_in[5];
    const float* Whh1 = (const float*)d_in[6];
    const float* bih1 = (const float*)d_in[7];
    const float* bhh1 = (const float*)d_in[8];
    const float* Wih2 = (const float*)d_in[9];
    const float* Whh2 = (const float*)d_in[10];
    const float* bih2 = (const float*)d_in[11];
    const float* bhh2 = (const float*)d_in[12];

    char* wsb = (char*)d_ws;
    float*          buf0  = (float*)wsb;
    uint32_t*       xr0   = (uint32_t*)(wsb + 33554432);
    unsigned short* relu1 = (unsigned short*)(wsb + 50331648);
    unsigned short* xp2h  = (unsigned short*)(wsb + 67108864);
    uint32_t*       hpk0  = (uint32_t*)(wsb + 71303168);
    uint32_t*       hpk1  = (uint32_t*)(wsb + 71434240);

    float* out = (float*)d_out;            // [32,512,128]
    float* hn  = out + NB * T_SEQ * 128;   // [1,32,128]

    const int M = NB * T_SEQ;  // 16384

    gemm_xp<<<dim3(M / BM, 512 / BN), 256, 0, stream>>>(x, Wih0, bih0, bhh0, buf0, M, 512, 128);
    rec01<<<512, 512, 0, stream>>>(Whh0, buf0, Wih1, Whh1, bih1, bhh1,
                                   xr0, relu1, hpk0, hpk1);
    gemm2h<<<dim3(M / BM, 1), 256, 0, stream>>>(relu1, Wih2, bih2, bhh2, xp2h, M, 512);
    rec128h<<<NB, 256, 0, stream>>>(Whh2, xp2h, out, hn);
}

// Round 11
// 1875.220 us; speedup vs baseline: 3.2231x; 1.6605x over previous
//
#include <hip/hip_runtime.h>
#include <hip/hip_fp16.h>
#include <cstdint>
#include <cstddef>
#include <cstring>

#define T_SEQ 512
#define NB 32

__device__ __forceinline__ uint32_t agent_load_u32(const uint32_t* p) {
    return __hip_atomic_load(p, __ATOMIC_RELAXED, __HIP_MEMORY_SCOPE_AGENT);
}
__device__ __forceinline__ void agent_store_u32(uint32_t* p, uint32_t v) {
    __hip_atomic_store(p, v, __ATOMIC_RELAXED, __HIP_MEMORY_SCOPE_AGENT);
}
__device__ __forceinline__ float hbits2f(unsigned short us) {
    __half h; __builtin_memcpy(&h, &us, 2); return __half2float(h);
}

// =====================================================================
// rec512_l0: layer-0 recurrence with FUSED input projection (no gemm0).
// 256 blocks = 8 slices x 32 batches, 1024 threads (16 waves, 1 blk/CU).
// Thread (jl=tid&63 -> row s*64+jl, kq=tid>>6 in 0..15 -> 32-wide k-chunk).
// VGPR weights: wh[16 half2] (Whh0 row, 32 k) + wi[4 half2] (Wih0 row,
// 8 of 128 k) = 20 half2 — safely under the ~92-reg remat cliff (law r7).
// h exchange: r7's parity-tagged agent-scope protocol, 2 barriers/step.
// Output: relu(h0) as fp16 bits to r0h[NB][T][512] (plain stores; next
// kernel reads after kernel boundary -> coherent).
// =====================================================================
__global__ __launch_bounds__(1024, 2) void rec512_l0(
    const float* __restrict__ x,       // [NB,T,128] fp32
    const float* __restrict__ Wih0,    // [512,128]
    const float* __restrict__ Whh0,    // [512,512]
    const float* __restrict__ bih0, const float* __restrict__ bhh0,
    unsigned short* __restrict__ r0h,  // [NB][T][512] fp16 bits
    uint32_t* __restrict__ hpk)        // [NB][2][512]
{
    const int tid = threadIdx.x;
    const int b  = blockIdx.x & 31;
    const int s  = blockIdx.x >> 5;    // 0..7
    const int jl = tid & 63;
    const int kq = tid >> 6;           // 0..15, wave-uniform
    const int row = (s << 6) + jl;

    __shared__ float hbuf[2][512];
    __shared__ float xbuf[2][128];
    __shared__ float part[16][64];

    __half2 wh[16], wi[4];
    {
        const float4* p4 = (const float4*)(Whh0 + (size_t)row * 512 + (kq << 5));
#pragma unroll
        for (int i = 0; i < 8; i++) {
            const float4 v = p4[i];
            wh[2 * i]     = __floats2half2_rn(v.x, v.y);
            wh[2 * i + 1] = __floats2half2_rn(v.z, v.w);
        }
        const float4* q4 = (const float4*)(Wih0 + (size_t)row * 128 + (kq << 3));
#pragma unroll
        for (int i = 0; i < 2; i++) {
            const float4 v = q4[i];
            wi[2 * i]     = __floats2half2_rn(v.x, v.y);
            wi[2 * i + 1] = __floats2half2_rn(v.z, v.w);
        }
    }
    float bias = 0.f;
    if (tid < 64) { const int r = (s << 6) + tid; bias = bih0[r] + bhh0[r]; }

    const float* x_b = x + (size_t)b * (T_SEQ * 128);
    unsigned short* r0_b = r0h + (size_t)b * (T_SEQ * 512);
    uint32_t* hp_b = hpk + (b << 10);
    const bool own = (kq == s);        // for tid<512 poll lanes
    const int myrow = (s << 6) + tid;  // epilogue lanes tid<64

    if (tid < 128) xbuf[0][tid] = x_b[tid];
    __syncthreads();

    for (int t = 0; t < T_SEQ; t++) {
        const int p = t & 1;
        // issue x(t+1) prefetch early (written to LDS after B1)
        float xn = 0.f;
        if (tid < 128 && t + 1 < T_SEQ) xn = x_b[(t + 1) * 128 + tid];

        if (t > 0 && tid < 512 && !own) {
            const uint32_t wtag = (uint32_t)t;
            uint32_t* sp = hp_b + (p << 9) + tid;
            uint32_t v;
            do { v = agent_load_u32(sp); } while ((v & 0xffffu) != wtag);
            hbuf[p][tid] = hbits2f((unsigned short)(v >> 16));
        }
        __syncthreads();   // B1: hbuf[p] ready; part[]/xbuf[p2] free
        if (tid < 128 && t + 1 < T_SEQ) xbuf[(t + 1) & 1][tid] = xn;

        float a0 = 0.f, a1 = 0.f, a2 = 0.f, a3 = 0.f;
        if (t > 0) {
            const float4* hq = (const float4*)(&hbuf[p][kq << 5]);
#pragma unroll
            for (int i = 0; i < 8; i++) {
                const float4 h4 = hq[i];
                a0 = fmaf(__low2float(wh[2 * i]),      h4.x, a0);
                a1 = fmaf(__high2float(wh[2 * i]),     h4.y, a1);
                a2 = fmaf(__low2float(wh[2 * i + 1]),  h4.z, a2);
                a3 = fmaf(__high2float(wh[2 * i + 1]), h4.w, a3);
            }
        }
        {
            const float4* xq = (const float4*)(&xbuf[p][kq << 3]);
#pragma unroll
            for (int i = 0; i < 2; i++) {
                const float4 x4 = xq[i];
                a0 = fmaf(__low2float(wi[2 * i]),      x4.x, a0);
                a1 = fmaf(__high2float(wi[2 * i]),     x4.y, a1);
                a2 = fmaf(__low2float(wi[2 * i + 1]),  x4.z, a2);
                a3 = fmaf(__high2float(wi[2 * i + 1]), x4.w, a3);
            }
        }
        part[kq][jl] = (a0 + a1) + (a2 + a3);
        __syncthreads();   // B2
        if (tid < 64) {
            const int p2 = (t + 1) & 1;
            float v = bias;
#pragma unroll
            for (int q = 0; q < 16; q++) v += part[q][tid];
            const float hv = tanhf(v);
            const __half hf = __float2half_rn(hv);
            unsigned short us; __builtin_memcpy(&us, &hf, 2);
            agent_store_u32(hp_b + (p2 << 9) + myrow,
                            ((uint32_t)us << 16) | (uint32_t)(t + 1));
            hbuf[p2][myrow] = hbits2f(us);
            r0_b[(size_t)t * 512 + myrow] = (us & 0x8000u) ? (unsigned short)0 : us;
        }
        // next step's B1 orders everything else
    }
}

// =====================================================================
// rec512_l1: layer-1 recurrence with FUSED input projection (no gemm1).
// Same shape as l0; input = relu0 fp16 (fully materialized, plain loads,
// staged+prefetched to LDS by lanes 512..767). Weights: wi[16]+wh[16]
// half2 = 32 — the exact r7-proven register scale.
// =====================================================================
__global__ __launch_bounds__(1024, 2) void rec512_l1(
    const unsigned short* __restrict__ r0h, // [NB][T][512] fp16 bits
    const float* __restrict__ Wih1,    // [512,512]
    const float* __restrict__ Whh1,    // [512,512]
    const float* __restrict__ bih1, const float* __restrict__ bhh1,
    unsigned short* __restrict__ r1h,  // [NB][T][512] fp16 bits
    uint32_t* __restrict__ hpk)        // [NB][2][512]
{
    const int tid = threadIdx.x;
    const int b  = blockIdx.x & 31;
    const int s  = blockIdx.x >> 5;
    const int jl = tid & 63;
    const int kq = tid >> 6;           // 0..15
    const int row = (s << 6) + jl;

    __shared__ float hbuf[2][512];
    __shared__ float rbuf[2][512];
    __shared__ float part[16][64];

    __half2 wi[16], wh[16];
    {
        const float4* p4 = (const float4*)(Wih1 + (size_t)row * 512 + (kq << 5));
#pragma unroll
        for (int i = 0; i < 8; i++) {
            const float4 v = p4[i];
            wi[2 * i]     = __floats2half2_rn(v.x, v.y);
            wi[2 * i + 1] = __floats2half2_rn(v.z, v.w);
        }
        p4 = (const float4*)(Whh1 + (size_t)row * 512 + (kq << 5));
#pragma unroll
        for (int i = 0; i < 8; i++) {
            const float4 v = p4[i];
            wh[2 * i]     = __floats2half2_rn(v.x, v.y);
            wh[2 * i + 1] = __floats2half2_rn(v.z, v.w);
        }
    }
    float bias = 0.f;
    if (tid < 64) { const int r = (s << 6) + tid; bias = bih1[r] + bhh1[r]; }

    const uint32_t* r0_b = (const uint32_t*)(r0h + (size_t)b * (T_SEQ * 512));
    unsigned short* r1_b = r1h + (size_t)b * (T_SEQ * 512);
    uint32_t* hp_b = hpk + (b << 10);
    const bool own = (kq == s);
    const int myrow = (s << 6) + tid;
    const int wlane = tid - 512;       // 0..255 staging lanes (tid 512..767)

    if (tid >= 512 && tid < 768) {
        const uint32_t v = r0_b[wlane];                 // r0(0) pairs
        rbuf[0][2 * wlane]     = hbits2f((unsigned short)(v & 0xffffu));
        rbuf[0][2 * wlane + 1] = hbits2f((unsigned short)(v >> 16));
    }
    __syncthreads();

    for (int t = 0; t < T_SEQ; t++) {
        const int p = t & 1;
        uint32_t rn = 0;
        if (tid >= 512 && tid < 768 && t + 1 < T_SEQ)
            rn = r0_b[(size_t)(t + 1) * 256 + wlane];   // prefetch r0(t+1)

        if (t > 0 && tid < 512 && !own) {
            const uint32_t wtag = (uint32_t)t;
            uint32_t* sp = hp_b + (p << 9) + tid;
            uint32_t v;
            do { v = agent_load_u32(sp); } while ((v & 0xffffu) != wtag);
            hbuf[p][tid] = hbits2f((unsigned short)(v >> 16));
        }
        __syncthreads();   // B1
        if (tid >= 512 && tid < 768 && t + 1 < T_SEQ) {
            rbuf[(t + 1) & 1][2 * wlane]     = hbits2f((unsigned short)(rn & 0xffffu));
            rbuf[(t + 1) & 1][2 * wlane + 1] = hbits2f((unsigned short)(rn >> 16));
        }

        float a0 = 0.f, a1 = 0.f, a2 = 0.f, a3 = 0.f;
        {
            const float4* rq = (const float4*)(&rbuf[p][kq << 5]);
#pragma unroll
            for (int i = 0; i < 8; i++) {
                const float4 h4 = rq[i];
                a0 = fmaf(__low2float(wi[2 * i]),      h4.x, a0);
                a1 = fmaf(__high2float(wi[2 * i]),     h4.y, a1);
                a2 = fmaf(__low2float(wi[2 * i + 1]),  h4.z, a2);
                a3 = fmaf(__high2float(wi[2 * i + 1]), h4.w, a3);
            }
        }
        if (t > 0) {
            const float4* hq = (const float4*)(&hbuf[p][kq << 5]);
#pragma unroll
            for (int i = 0; i < 8; i++) {
                const float4 h4 = hq[i];
                a0 = fmaf(__low2float(wh[2 * i]),      h4.x, a0);
                a1 = fmaf(__high2float(wh[2 * i]),     h4.y, a1);
                a2 = fmaf(__low2float(wh[2 * i + 1]),  h4.z, a2);
                a3 = fmaf(__high2float(wh[2 * i + 1]), h4.w, a3);
            }
        }
        part[kq][jl] = (a0 + a1) + (a2 + a3);
        __syncthreads();   // B2
        if (tid < 64) {
            const int p2 = (t + 1) & 1;
            float v = bias;
#pragma unroll
            for (int q = 0; q < 16; q++) v += part[q][tid];
            const float hv = tanhf(v);
            const __half hf = __float2half_rn(hv);
            unsigned short us; __builtin_memcpy(&us, &hf, 2);
            agent_store_u32(hp_b + (p2 << 9) + myrow,
                            ((uint32_t)us << 16) | (uint32_t)(t + 1));
            hbuf[p2][myrow] = hbits2f(us);
            r1_b[(size_t)t * 512 + myrow] = (us & 0x8000u) ? (unsigned short)0 : us;
        }
    }
}

// =====================================================================
// gemm2h: xp2 = relu1(fp16) @ Wih2^T + (bi+bh), fp16 out. (proven r10)
// =====================================================================
#define BM 64
#define BK 32
#define AS_STRIDE 68
#define BS_STRIDE 132

__global__ __launch_bounds__(256, 4) void gemm2h(
    const unsigned short* __restrict__ A,   // [M,512] fp16 bits
    const float* __restrict__ W,            // [128,512]
    const float* __restrict__ bi, const float* __restrict__ bh,
    unsigned short* __restrict__ C,         // [M,128] fp16 bits
    int M, int K)
{
    __shared__ float As[BK][AS_STRIDE];
    __shared__ float Bs[BK][BS_STRIDE];
    const int tid = threadIdx.x;
    const int tx = tid & 15, ty = tid >> 4;
    const int m0 = blockIdx.x * BM;
    const int lr = tid >> 3, lc = (tid & 7) << 2;

    float acc[4][8];
#pragma unroll
    for (int i = 0; i < 4; i++)
#pragma unroll
        for (int j = 0; j < 8; j++) acc[i][j] = 0.f;

    for (int k0 = 0; k0 < K; k0 += BK) {
#pragma unroll
        for (int p = 0; p < 2; p++) {
            const int m = p * 32 + lr;
            const uint2 u = *(const uint2*)(A + (size_t)(m0 + m) * K + k0 + lc);
            As[lc + 0][m] = hbits2f((unsigned short)(u.x & 0xffffu));
            As[lc + 1][m] = hbits2f((unsigned short)(u.x >> 16));
            As[lc + 2][m] = hbits2f((unsigned short)(u.y & 0xffffu));
            As[lc + 3][m] = hbits2f((unsigned short)(u.y >> 16));
        }
#pragma unroll
        for (int p = 0; p < 4; p++) {
            const int n = p * 32 + lr;
            const float4 b4 = *(const float4*)(W + (size_t)n * K + k0 + lc);
            Bs[lc + 0][n] = b4.x; Bs[lc + 1][n] = b4.y;
            Bs[lc + 2][n] = b4.z; Bs[lc + 3][n] = b4.w;
        }
        __syncthreads();
#pragma unroll
        for (int kk = 0; kk < BK; kk++) {
            const float4 a4  = *(const float4*)&As[kk][tx << 2];
            const float4 b4a = *(const float4*)&Bs[kk][ty << 3];
            const float4 b4b = *(const float4*)&Bs[kk][(ty << 3) + 4];
            const float a[4] = { a4.x, a4.y, a4.z, a4.w };
            const float b[8] = { b4a.x, b4a.y, b4a.z, b4a.w, b4b.x, b4b.y, b4b.z, b4b.w };
#pragma unroll
            for (int i = 0; i < 4; i++)
#pragma unroll
                for (int j = 0; j < 8; j++) acc[i][j] = fmaf(a[i], b[j], acc[i][j]);
        }
        __syncthreads();
    }
    const int nbase = ty << 3;
    const float4 bia = *(const float4*)(bi + nbase);
    const float4 bib = *(const float4*)(bi + nbase + 4);
    const float4 bha = *(const float4*)(bh + nbase);
    const float4 bhb = *(const float4*)(bh + nbase + 4);
    const float bt[8] = { bia.x + bha.x, bia.y + bha.y, bia.z + bha.z, bia.w + bha.w,
                          bib.x + bhb.x, bib.y + bhb.y, bib.z + bhb.z, bib.w + bhb.w };
#pragma unroll
    for (int i = 0; i < 4; i++) {
        const int row = m0 + (tx << 2) + i;
        uint32_t pk[4];
#pragma unroll
        for (int j = 0; j < 4; j++) {
            const __half hlo = __float2half_rn(acc[i][2 * j]     + bt[2 * j]);
            const __half hhi = __float2half_rn(acc[i][2 * j + 1] + bt[2 * j + 1]);
            unsigned short lo, hi;
            __builtin_memcpy(&lo, &hlo, 2); __builtin_memcpy(&hi, &hhi, 2);
            pk[j] = ((uint32_t)hi << 16) | lo;
        }
        *(uint4*)(C + (size_t)row * 128 + nbase) = make_uint4(pk[0], pk[1], pk[2], pk[3]);
    }
}

// =====================================================================
// Layer 2 recurrence (H=128), xp fp16. One WG/batch; LDS-only. (proven)
// =====================================================================
__global__ __launch_bounds__(256, 4) void rec128h(
    const float* __restrict__ Whh,          // [128,128]
    const unsigned short* __restrict__ xp,  // [NB,T,128] fp16 bits
    float* __restrict__ out,                // [NB,T,128]
    float* __restrict__ hn)                 // [NB,128]
{
    const int tid = threadIdx.x;
    const int b  = blockIdx.x;
    const int j  = tid & 127;
    const int kh = tid >> 7;

    __shared__ float hbuf[2][128];
    __shared__ float part[2][128];

    float w[64];
    {
        const float4* wp = (const float4*)(Whh + (size_t)j * 128 + (kh << 6));
#pragma unroll
        for (int i = 0; i < 16; i++) {
            const float4 v = wp[i];
            w[4 * i + 0] = v.x; w[4 * i + 1] = v.y;
            w[4 * i + 2] = v.z; w[4 * i + 3] = v.w;
        }
    }

    const unsigned short* xp_b = xp + (size_t)b * (T_SEQ * 128);
    float* out_b = out + (size_t)b * (T_SEQ * 128);

    float xpv = (tid < 128) ? hbits2f(xp_b[tid]) : 0.f;

    for (int t = 0; t < T_SEQ; t++) {
        float xpn = (tid < 128 && t + 1 < T_SEQ) ? hbits2f(xp_b[(t + 1) * 128 + tid]) : 0.f;

        float a0 = 0.f, a1 = 0.f, a2 = 0.f, a3 = 0.f;
        if (t > 0) {
            const float4* hq = (const float4*)(&hbuf[t & 1][kh << 6]);
#pragma unroll
            for (int i = 0; i < 16; i++) {
                const float4 h4 = hq[i];
                a0 = fmaf(w[4 * i + 0], h4.x, a0);
                a1 = fmaf(w[4 * i + 1], h4.y, a1);
                a2 = fmaf(w[4 * i + 2], h4.z, a2);
                a3 = fmaf(w[4 * i + 3], h4.w, a3);
            }
        }
        part[kh][j] = (a0 + a1) + (a2 + a3);
        __syncthreads();
        if (tid < 128) {
            const float v = part[0][tid] + part[1][tid] + xpv;
            const float h = tanhf(v);
            hbuf[(t + 1) & 1][tid] = h;
            out_b[t * 128 + tid] = h;
            if (t == T_SEQ - 1) hn[b * 128 + tid] = h;
        }
        __syncthreads();
        xpv = xpn;
    }
}

// =====================================================================
// Launch.  ws (bytes): r0h@0 16MB | r1h@16MB 16MB | xp2h@32MB 4MB |
//                      hpk0@37,748,736 128KB | hpk1@37,879,808 128KB
// =====================================================================
extern "C" void kernel_launch(void* const* d_in, const int* in_sizes, int n_in,
                              void* d_out, int out_size, void* d_ws, size_t ws_size,
                              hipStream_t stream)
{
    const float* x    = (const float*)d_in[0];
    const float* Wih0 = (const float*)d_in[1];
    const float* Whh0 = (const float*)d_in[2];
    const float* bih0 = (const float*)d_in[3];
    const float* bhh0 = (const float*)d_in[4];
    const float* Wih1 = (const float*)d_in[5];
    const float* Whh1 = (const float*)d_in[6];
    const float* bih1 = (const float*)d_in[7];
    const float* bhh1 = (const float*)d_in[8];
    const float* Wih2 = (const float*)d_in[9];
    const float* Whh2 = (const float*)d_in[10];
    const float* bih2 = (const float*)d_in[11];
    const float* bhh2 = (const float*)d_in[12];

    char* wsb = (char*)d_ws;
    unsigned short* r0h  = (unsigned short*)wsb;
    unsigned short* r1h  = (unsigned short*)(wsb + 16777216);
    unsigned short* xp2h = (unsigned short*)(wsb + 33554432);
    uint32_t*       hpk0 = (uint32_t*)(wsb + 37748736);
    uint32_t*       hpk1 = (uint32_t*)(wsb + 37879808);

    float* out = (float*)d_out;            // [32,512,128]
    float* hn  = out + NB * T_SEQ * 128;   // [1,32,128]

    const int M = NB * T_SEQ;  // 16384

    rec512_l0<<<NB * 8, 1024, 0, stream>>>(x, Wih0, Whh0, bih0, bhh0, r0h, hpk0);
    rec512_l1<<<NB * 8, 1024, 0, stream>>>(r0h, Wih1, Whh1, bih1, bhh1, r1h, hpk1);
    gemm2h<<<dim3(M / BM, 1), 256, 0, stream>>>(r1h, Wih2, bih2, bhh2, xp2h, M, 512);
    rec128h<<<NB, 256, 0, stream>>>(Whh2, xp2h, out, hn);
}